// Round 6
// baseline (196.426 us; speedup 1.0000x reference)
//
#include <hip/hip_runtime.h>
#include <hip/hip_bf16.h>
#include <stdint.h>

typedef __bf16 bf16x8 __attribute__((ext_vector_type(8)));
typedef float  f32x16 __attribute__((ext_vector_type(16)));
typedef float  f32x4  __attribute__((ext_vector_type(4)));

static constexpr int Bz = 2, Nn = 4096, Ee = 4, Dd = 64, ADim = 32;
static constexpr int Mm = Nn * Ee;        // 16384 reduction dim
static constexpr int KSEG = 8;            // K-segments
static constexpr int KLEN = Mm / KSEG;    // 2048 k per segment
static constexpr int NT = Bz * Nn / 32;   // 256 output row-tiles
static constexpr size_t SEGSTRIDE = (size_t)NT * 32 * 64;  // floats per kseg partial

__device__ __forceinline__ bf16x8 cvt8(float4 a, float4 b) {
  bf16x8 r;
  r[0] = (__bf16)a.x; r[1] = (__bf16)a.y; r[2] = (__bf16)a.z; r[3] = (__bf16)a.w;
  r[4] = (__bf16)b.x; r[5] = (__bf16)b.y; r[6] = (__bf16)b.z; r[7] = (__bf16)b.w;
  return r;
}
__device__ __forceinline__ bf16x8 cvt8v(f32x4 a, f32x4 b) {
  bf16x8 r;
  r[0] = (__bf16)a[0]; r[1] = (__bf16)a[1]; r[2] = (__bf16)a[2]; r[3] = (__bf16)a[3];
  r[4] = (__bf16)b[0]; r[5] = (__bf16)b[1]; r[6] = (__bf16)b[2]; r[7] = (__bf16)b[3];
  return r;
}
__device__ __forceinline__ f32x16 zero16() {
  f32x16 z;
#pragma unroll
  for (int i = 0; i < 16; ++i) z[i] = 0.f;
  return z;
}
__device__ __forceinline__ f32x16 mm(bf16x8 a, bf16x8 b, f32x16 c) {
  return __builtin_amdgcn_mfma_f32_32x32x16_bf16(a, b, c, 0, 0, 0);
}
__device__ __forceinline__ float sigm(float x) { return 1.f / (1.f + __expf(-x)); }
__device__ __forceinline__ float tanh_fast(float x) {
  float e = __expf(2.f * x);
  return 1.f - 2.f / (e + 1.f);
}
__device__ __forceinline__ void async_lds16(const void* g, void* l) {
  __builtin_amdgcn_global_load_lds(
      (const __attribute__((address_space(1))) uint32_t*)g,
      (__attribute__((address_space(3))) uint32_t*)l, 16, 0, 0);
}

// -------- Kernel 0: pack GRU/head weights into bf16 MFMA B-fragments.
__global__ __launch_bounds__(64) void k_pack(
    const float* __restrict__ Wr, const float* __restrict__ Wz,
    const float* __restrict__ Wh, const float* __restrict__ Wo1,
    __bf16* __restrict__ Wp) {
  const int f = blockIdx.x, l = threadIdx.x;
  const int r31 = l & 31, h = l >> 5;
  const float* W; int L, fl;
  if (f < 16)      { W = Wr;  L = 128; fl = f; }
  else if (f < 32) { W = Wz;  L = 128; fl = f - 16; }
  else if (f < 48) { W = Wh;  L = 128; fl = f - 32; }
  else             { W = Wo1; L = 96;  fl = f - 48; }
  const int ks = fl >> 1, oh = fl & 1;
  const float* src = W + (size_t)(32 * oh + r31) * L + 16 * ks + 8 * h;
  float4 s0 = *reinterpret_cast<const float4*>(src);
  float4 s1 = *reinterpret_cast<const float4*>(src + 4);
  *reinterpret_cast<bf16x8*>(Wp + ((size_t)f * 64 + l) * 8) = cvt8(s0, s1);
}

// -------- Kernel 1: Bt[b][d][e*N+n] = sum_d' W_in[e][d][d'] * prop[b][n][d'] + b_in[e][d]
__global__ __launch_bounds__(256) void k_build_bt(
    const float* __restrict__ prop, const float* __restrict__ Win,
    const float* __restrict__ bin, __bf16* __restrict__ Bt) {
  const int nchunk = blockIdx.x;
  const int e = blockIdx.y, b = blockIdx.z;
  const int tid = threadIdx.x;
  const int w = tid >> 6, l = tid & 63;
  const int r31 = l & 31, h = l >> 5;
  const int oh = w & 1, ns = w >> 1;
  const int o_row = oh * 32 + r31;
  const int n_col = nchunk * 64 + ns * 32 + r31;
  const float* wbase = Win + ((size_t)e * 64 + o_row) * 64 + 8 * h;
  const float* pbase = prop + ((size_t)b * Nn + n_col) * 64 + 8 * h;
  f32x16 acc = zero16();
#pragma unroll
  for (int ks = 0; ks < 4; ++ks) {
    float4 w0 = *reinterpret_cast<const float4*>(wbase + 16 * ks);
    float4 w1 = *reinterpret_cast<const float4*>(wbase + 16 * ks + 4);
    float4 p0 = *reinterpret_cast<const float4*>(pbase + 16 * ks);
    float4 p1 = *reinterpret_cast<const float4*>(pbase + 16 * ks + 4);
    acc = mm(cvt8(w0, w1), cvt8(p0, p1), acc);
  }
#pragma unroll
  for (int reg = 0; reg < 16; ++reg) {
    int orow = oh * 32 + (reg & 3) + 8 * (reg >> 2) + 4 * h;
    float v = acc[reg] + bin[e * 64 + orow];
    Bt[((size_t)b * 64 + orow) * Mm + (size_t)e * Nn + n_col] = (__bf16)v;
  }
}

// -------- Kernel 2: split-K GEMM with Bt slice staged in LDS.
// 256 blocks (1/CU), 8 waves. kseg = bid&7; 8 tiles/block (same batch),
// wave w owns tile (g + 16w) end-to-end (no cross-wave reduce).
// Bt slice [64][2048] bf16 staged in 4 phases of 64 KB via global_load_lds,
// source pre-swizzled (unit ^= row&7) so swizzled ds_read_b128 is
// conflict-free (each bank gets exactly 8 words per read). Bt HBM traffic
// bounded at 256 x 256 KB = 64 MB by construction; A streamed once.
__global__ __launch_bounds__(512, 2) void k_big_gemm(
    const float* __restrict__ A, const __bf16* __restrict__ Bt,
    float* __restrict__ part) {
  __shared__ __bf16 btl[64][512];   // 64 KB
  const int bid = blockIdx.x;       // 0..255
  const int kseg = bid & 7;
  const int grp  = bid >> 3;        // 0..31
  const int bb   = grp >> 4;        // batch
  const int g    = grp & 15;
  const int tid = threadIdx.x;
  const int w = tid >> 6, l = tid & 63;
  const int r31 = l & 31, h = l >> 5;
  const int tile = bb * 128 + g + 16 * w;   // this wave's output tile
  const int n0 = (g + 16 * w) * 32;
  const size_t kbase = (size_t)kseg * KLEN;

  const float* ap = A + ((size_t)(bb * Nn + n0 + r31)) * Mm + kbase + 8 * h;
  const __bf16* BtB = Bt + (size_t)bb * 64 * Mm + kbase;

  f32x16 acc0 = zero16(), acc1 = zero16();

  for (int p = 0; p < 4; ++p) {
    if (p) __syncthreads();          // prior phase's LDS reads done
    // stage 64 rows x 512 k bf16 = 64 KB; wave w loads rows 8w..8w+7
#pragma unroll
    for (int j = 0; j < 8; ++j) {
      const int row = 8 * w + j;
      const int ug = l ^ (row & 7);  // pre-swizzled global 16B-unit
      const __bf16* src = BtB + (size_t)row * Mm + p * 512 + ug * 8;
      async_lds16(src, &btl[row][0]);
    }
    asm volatile("s_waitcnt vmcnt(0)" ::: "memory");
    __syncthreads();
    // 32 K-steps (16 k each) against LDS Bt
#pragma unroll 8
    for (int s = 0; s < 32; ++s) {
      float4 a0 = *reinterpret_cast<const float4*>(ap);
      float4 a1 = *reinterpret_cast<const float4*>(ap + 4);
      bf16x8 fa = cvt8(a0, a1);
      const int su = (2 * s + h) ^ (r31 & 7);
      bf16x8 fb0 = *reinterpret_cast<const bf16x8*>(&btl[r31][su * 8]);
      bf16x8 fb1 = *reinterpret_cast<const bf16x8*>(&btl[32 + r31][su * 8]);
      acc0 = mm(fa, fb0, acc0);
      acc1 = mm(fa, fb1, acc1);
      ap += 16;
    }
  }
  // write 32x64 partial for this wave's tile
  float* pb = part + (size_t)kseg * SEGSTRIDE + (size_t)tile * 32 * 64;
#pragma unroll
  for (int reg = 0; reg < 16; ++reg) {
    int row = (reg & 3) + 8 * (reg >> 2) + 4 * h;
    pb[row * 64 + r31] = acc0[reg];
    pb[row * 64 + 32 + r31] = acc1[reg];
  }
}

// -------- Kernel 3: fold split-K reduce + GRU gate update + output head.
__global__ __launch_bounds__(64) void k_gru(
    const float* __restrict__ part, const float* __restrict__ prop,
    const float* __restrict__ annot, const __bf16* __restrict__ Wp,
    const float* __restrict__ br, const float* __restrict__ bz,
    const float* __restrict__ bh, const float* __restrict__ bo1,
    const float* __restrict__ Wo2, const float* __restrict__ bo2,
    float* __restrict__ out) {
  __shared__ float plds[32][68];
  __shared__ float tlds[32][68];
  const int tile = blockIdx.x;
  const int R0 = tile * 32;
  const int l = threadIdx.x;
  const int r31 = l & 31, h = l >> 5;

  bf16x8 xa[4], xp[4], xan[2];
  {
    const float* pt = part + ((size_t)tile * 32 + r31) * 64 + 8 * h;
    const float* pb = prop + (size_t)(R0 + r31) * 64 + 8 * h;
#pragma unroll
    for (int ks = 0; ks < 4; ++ks) {
      f32x4 s0, s1;
      s0[0] = s0[1] = s0[2] = s0[3] = 0.f;
      s1[0] = s1[1] = s1[2] = s1[3] = 0.f;
#pragma unroll
      for (int seg = 0; seg < 8; ++seg) {
        const float* pp = pt + seg * SEGSTRIDE + 16 * ks;
        f32x4 v0 = *reinterpret_cast<const f32x4*>(pp);
        f32x4 v1 = *reinterpret_cast<const f32x4*>(pp + 4);
        s0[0] += v0[0]; s0[1] += v0[1]; s0[2] += v0[2]; s0[3] += v0[3];
        s1[0] += v1[0]; s1[1] += v1[1]; s1[2] += v1[2]; s1[3] += v1[3];
      }
      xa[ks] = cvt8v(s0, s1);
      float4 p0 = *reinterpret_cast<const float4*>(pb + 16 * ks);
      float4 p1 = *reinterpret_cast<const float4*>(pb + 16 * ks + 4);
      xp[ks] = cvt8(p0, p1);
      *reinterpret_cast<float4*>(&plds[r31][16 * ks + 8 * h]) = p0;
      *reinterpret_cast<float4*>(&plds[r31][16 * ks + 8 * h + 4]) = p1;
    }
    const float* anb = annot + (size_t)(R0 + r31) * ADim + 8 * h;
#pragma unroll
    for (int ks = 0; ks < 2; ++ks) {
      float4 a0 = *reinterpret_cast<const float4*>(anb + 16 * ks);
      float4 a1 = *reinterpret_cast<const float4*>(anb + 16 * ks + 4);
      xan[ks] = cvt8(a0, a1);
    }
  }
  __syncthreads();

#define LDWP(base, ks, oh) \
  (*reinterpret_cast<const bf16x8*>(Wp + (((size_t)(base) + (ks) * 2 + (oh)) * 64 + l) * 8))

  f32x16 aR[2] = {zero16(), zero16()}, aZ[2] = {zero16(), zero16()};
#pragma unroll
  for (int ks = 0; ks < 8; ++ks) {
    bf16x8 af = (ks < 4) ? xa[ks] : xp[ks - 4];
#pragma unroll
    for (int oh = 0; oh < 2; ++oh) {
      aR[oh] = mm(af, LDWP(0, ks, oh), aR[oh]);
      aZ[oh] = mm(af, LDWP(16, ks, oh), aZ[oh]);
    }
  }
  const float br_[2] = {br[r31], br[32 + r31]};
  const float bz_[2] = {bz[r31], bz[32 + r31]};
  float propv[2][16], zv[2][16];
#pragma unroll
  for (int oh = 0; oh < 2; ++oh) {
#pragma unroll
    for (int reg = 0; reg < 16; ++reg) {
      int row = (reg & 3) + 8 * (reg >> 2) + 4 * h;
      int o = 32 * oh + r31;
      propv[oh][reg] = plds[row][o];
      float rv = sigm(aR[oh][reg] + br_[oh]);
      zv[oh][reg] = sigm(aZ[oh][reg] + bz_[oh]);
      tlds[row][o] = rv * propv[oh][reg];
    }
  }
  __syncthreads();
  bf16x8 xr[4];
#pragma unroll
  for (int ks = 0; ks < 4; ++ks) {
    float4 t0 = *reinterpret_cast<const float4*>(&tlds[r31][16 * ks + 8 * h]);
    float4 t1 = *reinterpret_cast<const float4*>(&tlds[r31][16 * ks + 8 * h + 4]);
    xr[ks] = cvt8(t0, t1);
  }
  f32x16 aH[2] = {zero16(), zero16()};
#pragma unroll
  for (int ks = 0; ks < 8; ++ks) {
    bf16x8 af = (ks < 4) ? xa[ks] : xr[ks - 4];
#pragma unroll
    for (int oh = 0; oh < 2; ++oh) aH[oh] = mm(af, LDWP(32, ks, oh), aH[oh]);
  }
  __syncthreads();
  const float bh_[2] = {bh[r31], bh[32 + r31]};
#pragma unroll
  for (int oh = 0; oh < 2; ++oh) {
#pragma unroll
    for (int reg = 0; reg < 16; ++reg) {
      int row = (reg & 3) + 8 * (reg >> 2) + 4 * h;
      int o = 32 * oh + r31;
      float hh = tanh_fast(aH[oh][reg] + bh_[oh]);
      float z = zv[oh][reg];
      tlds[row][o] = (1.f - z) * propv[oh][reg] + z * hh;
    }
  }
  __syncthreads();
  bf16x8 xn[4];
#pragma unroll
  for (int ks = 0; ks < 4; ++ks) {
    float4 t0 = *reinterpret_cast<const float4*>(&tlds[r31][16 * ks + 8 * h]);
    float4 t1 = *reinterpret_cast<const float4*>(&tlds[r31][16 * ks + 8 * h + 4]);
    xn[ks] = cvt8(t0, t1);
  }
  f32x16 aO[2] = {zero16(), zero16()};
#pragma unroll
  for (int ks = 0; ks < 6; ++ks) {
    bf16x8 af = (ks < 4) ? xn[ks] : xan[ks - 4];
#pragma unroll
    for (int oh = 0; oh < 2; ++oh) aO[oh] = mm(af, LDWP(48, ks, oh), aO[oh]);
  }
  const float bo1_[2] = {bo1[r31], bo1[32 + r31]};
  const float wo2_[2] = {Wo2[r31], Wo2[32 + r31]};
  const float bo2v = bo2[0];
#pragma unroll
  for (int reg = 0; reg < 16; ++reg) {
    float h0 = tanh_fast(aO[0][reg] + bo1_[0]);
    float h1 = tanh_fast(aO[1][reg] + bo1_[1]);
    float p = h0 * wo2_[0] + h1 * wo2_[1];
#pragma unroll
    for (int mks = 16; mks >= 1; mks >>= 1) p += __shfl_xor(p, mks, 64);
    if (r31 == 0) {
      int row = (reg & 3) + 8 * (reg >> 2) + 4 * h;
      out[R0 + row] = p + bo2v;
    }
  }
#undef LDWP
}

extern "C" void kernel_launch(void* const* d_in, const int* in_sizes, int n_in,
                              void* d_out, int out_size, void* d_ws, size_t ws_size,
                              hipStream_t stream) {
  const float* prop  = (const float*)d_in[0];
  const float* annot = (const float*)d_in[1];
  const float* A     = (const float*)d_in[2];
  const float* Win   = (const float*)d_in[3];
  const float* bin   = (const float*)d_in[4];
  const float* Wr    = (const float*)d_in[5];
  const float* br    = (const float*)d_in[6];
  const float* Wz    = (const float*)d_in[7];
  const float* bz    = (const float*)d_in[8];
  const float* Wh    = (const float*)d_in[9];
  const float* bh    = (const float*)d_in[10];
  const float* Wo1   = (const float*)d_in[11];
  const float* bo1   = (const float*)d_in[12];
  const float* Wo2   = (const float*)d_in[13];
  const float* bo2   = (const float*)d_in[14];
  float* out = (float*)d_out;

  char* ws = (char*)d_ws;
  __bf16* Bt   = (__bf16*)ws;                              // [2][64][16384] bf16 = 4 MB
  float*  part = (float*)(ws + (size_t)4 * 1024 * 1024);   // [8][256][32][64] f32 = 16 MB
  __bf16* Wp   = (__bf16*)(ws + (size_t)20 * 1024 * 1024); // 60 KB

  k_pack<<<dim3(60), 64, 0, stream>>>(Wr, Wz, Wh, Wo1, Wp);
  k_build_bt<<<dim3(Nn / 64, Ee, Bz), 256, 0, stream>>>(prop, Win, bin, Bt);
  k_big_gemm<<<dim3(256), 512, 0, stream>>>(A, Bt, part);
  k_gru<<<dim3(NT), 64, 0, stream>>>(part, prop, annot, Wp,
                                     br, bz, bh, bo1, Wo2, bo2, out);
}

// Round 7
// 173.813 us; speedup vs baseline: 1.1301x; 1.1301x over previous
//
#include <hip/hip_runtime.h>
#include <hip/hip_bf16.h>
#include <stdint.h>

typedef __bf16 bf16x8 __attribute__((ext_vector_type(8)));
typedef float  f32x16 __attribute__((ext_vector_type(16)));
typedef float  f32x4  __attribute__((ext_vector_type(4)));

static constexpr int Bz = 2, Nn = 4096, Ee = 4, Dd = 64, ADim = 32;
static constexpr int Mm = Nn * Ee;        // 16384 reduction dim
static constexpr int KSEG = 8;            // K-segments
static constexpr int KLEN = Mm / KSEG;    // 2048 k per segment
static constexpr int NT = Bz * Nn / 32;   // 256 output row-tiles
static constexpr size_t SEGSTRIDE = (size_t)NT * 32 * 64;  // floats per kseg partial
static constexpr int PHK = 128;           // k per phase
static constexpr int NPH = KLEN / PHK;    // 16 phases

__device__ __forceinline__ bf16x8 cvt8(float4 a, float4 b) {
  bf16x8 r;
  r[0] = (__bf16)a.x; r[1] = (__bf16)a.y; r[2] = (__bf16)a.z; r[3] = (__bf16)a.w;
  r[4] = (__bf16)b.x; r[5] = (__bf16)b.y; r[6] = (__bf16)b.z; r[7] = (__bf16)b.w;
  return r;
}
__device__ __forceinline__ bf16x8 cvt8v(f32x4 a, f32x4 b) {
  bf16x8 r;
  r[0] = (__bf16)a[0]; r[1] = (__bf16)a[1]; r[2] = (__bf16)a[2]; r[3] = (__bf16)a[3];
  r[4] = (__bf16)b[0]; r[5] = (__bf16)b[1]; r[6] = (__bf16)b[2]; r[7] = (__bf16)b[3];
  return r;
}
__device__ __forceinline__ f32x16 zero16() {
  f32x16 z;
#pragma unroll
  for (int i = 0; i < 16; ++i) z[i] = 0.f;
  return z;
}
__device__ __forceinline__ f32x16 mm(bf16x8 a, bf16x8 b, f32x16 c) {
  return __builtin_amdgcn_mfma_f32_32x32x16_bf16(a, b, c, 0, 0, 0);
}
__device__ __forceinline__ float sigm(float x) { return 1.f / (1.f + __expf(-x)); }
__device__ __forceinline__ float tanh_fast(float x) {
  float e = __expf(2.f * x);
  return 1.f - 2.f / (e + 1.f);
}
__device__ __forceinline__ void async_lds16(const void* g, void* l) {
  __builtin_amdgcn_global_load_lds(
      (const __attribute__((address_space(1))) uint32_t*)g,
      (__attribute__((address_space(3))) uint32_t*)l, 16, 0, 0);
}

// -------- Kernel 0: pack GRU/head weights into bf16 MFMA B-fragments.
__global__ __launch_bounds__(64) void k_pack(
    const float* __restrict__ Wr, const float* __restrict__ Wz,
    const float* __restrict__ Wh, const float* __restrict__ Wo1,
    __bf16* __restrict__ Wp) {
  const int f = blockIdx.x, l = threadIdx.x;
  const int r31 = l & 31, h = l >> 5;
  const float* W; int L, fl;
  if (f < 16)      { W = Wr;  L = 128; fl = f; }
  else if (f < 32) { W = Wz;  L = 128; fl = f - 16; }
  else if (f < 48) { W = Wh;  L = 128; fl = f - 32; }
  else             { W = Wo1; L = 96;  fl = f - 48; }
  const int ks = fl >> 1, oh = fl & 1;
  const float* src = W + (size_t)(32 * oh + r31) * L + 16 * ks + 8 * h;
  float4 s0 = *reinterpret_cast<const float4*>(src);
  float4 s1 = *reinterpret_cast<const float4*>(src + 4);
  *reinterpret_cast<bf16x8*>(Wp + ((size_t)f * 64 + l) * 8) = cvt8(s0, s1);
}

// -------- Kernel 1: Bt[b][d][e*N+n] = sum_d' W_in[e][d][d'] * prop[b][n][d'] + b_in[e][d]
__global__ __launch_bounds__(256) void k_build_bt(
    const float* __restrict__ prop, const float* __restrict__ Win,
    const float* __restrict__ bin, __bf16* __restrict__ Bt) {
  const int nchunk = blockIdx.x;
  const int e = blockIdx.y, b = blockIdx.z;
  const int tid = threadIdx.x;
  const int w = tid >> 6, l = tid & 63;
  const int r31 = l & 31, h = l >> 5;
  const int oh = w & 1, ns = w >> 1;
  const int o_row = oh * 32 + r31;
  const int n_col = nchunk * 64 + ns * 32 + r31;
  const float* wbase = Win + ((size_t)e * 64 + o_row) * 64 + 8 * h;
  const float* pbase = prop + ((size_t)b * Nn + n_col) * 64 + 8 * h;
  f32x16 acc = zero16();
#pragma unroll
  for (int ks = 0; ks < 4; ++ks) {
    float4 w0 = *reinterpret_cast<const float4*>(wbase + 16 * ks);
    float4 w1 = *reinterpret_cast<const float4*>(wbase + 16 * ks + 4);
    float4 p0 = *reinterpret_cast<const float4*>(pbase + 16 * ks);
    float4 p1 = *reinterpret_cast<const float4*>(pbase + 16 * ks + 4);
    acc = mm(cvt8(w0, w1), cvt8(p0, p1), acc);
  }
#pragma unroll
  for (int reg = 0; reg < 16; ++reg) {
    int orow = oh * 32 + (reg & 3) + 8 * (reg >> 2) + 4 * h;
    float v = acc[reg] + bin[e * 64 + orow];
    Bt[((size_t)b * 64 + orow) * Mm + (size_t)e * Nn + n_col] = (__bf16)v;
  }
}

// -------- Kernel 2: split-K GEMM, BOTH operands LDS-staged with wave-contiguous
// global_load_lds issues (A: 1KB issues covering 2x512B row-segments; no 16B
// scattered requests anywhere). 256 blocks (1/CU), 8 waves; kseg = bid&7;
// wave w owns tile (g+16w) end-to-end. 16 phases of 128k, single-buffered.
// XOR swizzle u^=(row&7) applied on global source AND LDS read (both-sides):
// uniform 8 words/bank per ds_read_b128 -> conflict-free.
__global__ __launch_bounds__(512, 1) void k_big_gemm(
    const float* __restrict__ A, const __bf16* __restrict__ Bt,
    float* __restrict__ part) {
  __shared__ float  aw[8][32][PHK];     // 128 KB: per-wave private A tiles (f32)
  __shared__ __bf16 btl[64][PHK];       // 16 KB: shared Bt tile (bf16)

  const int bid = blockIdx.x;       // 0..255
  const int kseg = bid & 7;
  const int grp  = bid >> 3;        // 0..31
  const int bb   = grp >> 4;        // batch
  const int g    = grp & 15;
  const int tid = threadIdx.x;
  const int w = tid >> 6, l = tid & 63;
  const int r31 = l & 31, h = l >> 5;
  const int tile = bb * 128 + g + 16 * w;   // this wave's output tile
  const int n0 = (g + 16 * w) * 32;
  const size_t kbase = (size_t)kseg * KLEN;

  const float*  Abase = A + ((size_t)(bb * Nn + n0)) * Mm + kbase;  // wave's 32 rows
  const __bf16* BtB   = Bt + (size_t)bb * 64 * Mm + kbase;

  // A stage, phase p: 16 issues/wave; issue j: rows 2j,2j+1 (512B each).
  // lane l: row = 2j + (l>>5), unit u=(l&31); source unit pre-swizzled u^(row&7).
  const int arow_l = (l >> 5);          // 0/1 within issue
  const int auswz  = (l & 31);          // linear LDS unit
#define ISSUE_A(p)                                                          \
  {                                                                         \
    _Pragma("unroll")                                                       \
    for (int j_ = 0; j_ < 16; ++j_) {                                       \
      const int row_ = 2 * j_ + arow_l;                                     \
      const float* src_ = Abase + (size_t)row_ * Mm + (p) * PHK +           \
                          ((auswz ^ (row_ & 7)) * 4);                       \
      async_lds16(src_, (char*)&aw[w][0][0] + j_ * 1024);                   \
    }                                                                       \
  }
  // Bt stage, phase p: 2 issues/wave (i = 2w, 2w+1), 4 rows x 256B each.
  const int brow_l = (l >> 4);          // 0..3 within issue
  const int buswz  = (l & 15);
#define ISSUE_BT(p)                                                         \
  {                                                                         \
    _Pragma("unroll")                                                       \
    for (int i_ = 2 * w; i_ < 2 * w + 2; ++i_) {                            \
      const int row_ = 4 * i_ + brow_l;                                     \
      const __bf16* src_ = BtB + (size_t)row_ * Mm + (p) * PHK +            \
                           ((buswz ^ (row_ & 7)) * 8);                      \
      async_lds16(src_, (char*)&btl[0][0] + i_ * 1024);                     \
    }                                                                       \
  }

  f32x16 acc0 = zero16(), acc1 = zero16();
  ISSUE_A(0);
  ISSUE_BT(0);

  for (int p = 0; p < NPH; ++p) {
    asm volatile("s_waitcnt vmcnt(0)" ::: "memory");
    __syncthreads();                 // everyone's stage(p) complete
    const int swz = (r31 & 7);
#pragma unroll
    for (int s = 0; s < 8; ++s) {
      const int u0 = 4 * s + 2 * h;  // A 16B-unit (of 32)
      f32x4 fa0 = *reinterpret_cast<const f32x4*>(&aw[w][r31][(u0 ^ swz) * 4]);
      f32x4 fa1 = *reinterpret_cast<const f32x4*>(&aw[w][r31][((u0 + 1) ^ swz) * 4]);
      bf16x8 fa = cvt8v(fa0, fa1);
      const int bu = 2 * s + h;      // Bt 16B-unit (of 16)
      bf16x8 fb0 = *reinterpret_cast<const bf16x8*>(&btl[r31][(bu ^ swz) * 8]);
      bf16x8 fb1 = *reinterpret_cast<const bf16x8*>(&btl[32 + r31][(bu ^ swz) * 8]);
      acc0 = mm(fa, fb0, acc0);
      acc1 = mm(fa, fb1, acc1);
    }
    __syncthreads();                 // all waves done reading phase p LDS
    if (p + 1 < NPH) {
      ISSUE_A(p + 1);
      ISSUE_BT(p + 1);
    }
  }
#undef ISSUE_A
#undef ISSUE_BT

  // write 32x64 partial for this wave's tile
  float* pb = part + (size_t)kseg * SEGSTRIDE + (size_t)tile * 32 * 64;
#pragma unroll
  for (int reg = 0; reg < 16; ++reg) {
    int row = (reg & 3) + 8 * (reg >> 2) + 4 * h;
    pb[row * 64 + r31] = acc0[reg];
    pb[row * 64 + 32 + r31] = acc1[reg];
  }
}

// -------- Kernel 3: fold split-K reduce + GRU gate update + output head.
__global__ __launch_bounds__(64) void k_gru(
    const float* __restrict__ part, const float* __restrict__ prop,
    const float* __restrict__ annot, const __bf16* __restrict__ Wp,
    const float* __restrict__ br, const float* __restrict__ bz,
    const float* __restrict__ bh, const float* __restrict__ bo1,
    const float* __restrict__ Wo2, const float* __restrict__ bo2,
    float* __restrict__ out) {
  __shared__ float plds[32][68];
  __shared__ float tlds[32][68];
  const int tile = blockIdx.x;
  const int R0 = tile * 32;
  const int l = threadIdx.x;
  const int r31 = l & 31, h = l >> 5;

  bf16x8 xa[4], xp[4], xan[2];
  {
    const float* pt = part + ((size_t)tile * 32 + r31) * 64 + 8 * h;
    const float* pb = prop + (size_t)(R0 + r31) * 64 + 8 * h;
#pragma unroll
    for (int ks = 0; ks < 4; ++ks) {
      f32x4 s0, s1;
      s0[0] = s0[1] = s0[2] = s0[3] = 0.f;
      s1[0] = s1[1] = s1[2] = s1[3] = 0.f;
#pragma unroll
      for (int seg = 0; seg < 8; ++seg) {
        const float* pp = pt + seg * SEGSTRIDE + 16 * ks;
        f32x4 v0 = *reinterpret_cast<const f32x4*>(pp);
        f32x4 v1 = *reinterpret_cast<const f32x4*>(pp + 4);
        s0[0] += v0[0]; s0[1] += v0[1]; s0[2] += v0[2]; s0[3] += v0[3];
        s1[0] += v1[0]; s1[1] += v1[1]; s1[2] += v1[2]; s1[3] += v1[3];
      }
      xa[ks] = cvt8v(s0, s1);
      float4 p0 = *reinterpret_cast<const float4*>(pb + 16 * ks);
      float4 p1 = *reinterpret_cast<const float4*>(pb + 16 * ks + 4);
      xp[ks] = cvt8(p0, p1);
      *reinterpret_cast<float4*>(&plds[r31][16 * ks + 8 * h]) = p0;
      *reinterpret_cast<float4*>(&plds[r31][16 * ks + 8 * h + 4]) = p1;
    }
    const float* anb = annot + (size_t)(R0 + r31) * ADim + 8 * h;
#pragma unroll
    for (int ks = 0; ks < 2; ++ks) {
      float4 a0 = *reinterpret_cast<const float4*>(anb + 16 * ks);
      float4 a1 = *reinterpret_cast<const float4*>(anb + 16 * ks + 4);
      xan[ks] = cvt8(a0, a1);
    }
  }
  __syncthreads();

#define LDWP(base, ks, oh) \
  (*reinterpret_cast<const bf16x8*>(Wp + (((size_t)(base) + (ks) * 2 + (oh)) * 64 + l) * 8))

  f32x16 aR[2] = {zero16(), zero16()}, aZ[2] = {zero16(), zero16()};
#pragma unroll
  for (int ks = 0; ks < 8; ++ks) {
    bf16x8 af = (ks < 4) ? xa[ks] : xp[ks - 4];
#pragma unroll
    for (int oh = 0; oh < 2; ++oh) {
      aR[oh] = mm(af, LDWP(0, ks, oh), aR[oh]);
      aZ[oh] = mm(af, LDWP(16, ks, oh), aZ[oh]);
    }
  }
  const float br_[2] = {br[r31], br[32 + r31]};
  const float bz_[2] = {bz[r31], bz[32 + r31]};
  float propv[2][16], zv[2][16];
#pragma unroll
  for (int oh = 0; oh < 2; ++oh) {
#pragma unroll
    for (int reg = 0; reg < 16; ++reg) {
      int row = (reg & 3) + 8 * (reg >> 2) + 4 * h;
      int o = 32 * oh + r31;
      propv[oh][reg] = plds[row][o];
      float rv = sigm(aR[oh][reg] + br_[oh]);
      zv[oh][reg] = sigm(aZ[oh][reg] + bz_[oh]);
      tlds[row][o] = rv * propv[oh][reg];
    }
  }
  __syncthreads();
  bf16x8 xr[4];
#pragma unroll
  for (int ks = 0; ks < 4; ++ks) {
    float4 t0 = *reinterpret_cast<const float4*>(&tlds[r31][16 * ks + 8 * h]);
    float4 t1 = *reinterpret_cast<const float4*>(&tlds[r31][16 * ks + 8 * h + 4]);
    xr[ks] = cvt8(t0, t1);
  }
  f32x16 aH[2] = {zero16(), zero16()};
#pragma unroll
  for (int ks = 0; ks < 8; ++ks) {
    bf16x8 af = (ks < 4) ? xa[ks] : xr[ks - 4];
#pragma unroll
    for (int oh = 0; oh < 2; ++oh) aH[oh] = mm(af, LDWP(32, ks, oh), aH[oh]);
  }
  __syncthreads();
  const float bh_[2] = {bh[r31], bh[32 + r31]};
#pragma unroll
  for (int oh = 0; oh < 2; ++oh) {
#pragma unroll
    for (int reg = 0; reg < 16; ++reg) {
      int row = (reg & 3) + 8 * (reg >> 2) + 4 * h;
      int o = 32 * oh + r31;
      float hh = tanh_fast(aH[oh][reg] + bh_[oh]);
      float z = zv[oh][reg];
      tlds[row][o] = (1.f - z) * propv[oh][reg] + z * hh;
    }
  }
  __syncthreads();
  bf16x8 xn[4];
#pragma unroll
  for (int ks = 0; ks < 4; ++ks) {
    float4 t0 = *reinterpret_cast<const float4*>(&tlds[r31][16 * ks + 8 * h]);
    float4 t1 = *reinterpret_cast<const float4*>(&tlds[r31][16 * ks + 8 * h + 4]);
    xn[ks] = cvt8(t0, t1);
  }
  f32x16 aO[2] = {zero16(), zero16()};
#pragma unroll
  for (int ks = 0; ks < 6; ++ks) {
    bf16x8 af = (ks < 4) ? xn[ks] : xan[ks - 4];
#pragma unroll
    for (int oh = 0; oh < 2; ++oh) aO[oh] = mm(af, LDWP(48, ks, oh), aO[oh]);
  }
  const float bo1_[2] = {bo1[r31], bo1[32 + r31]};
  const float wo2_[2] = {Wo2[r31], Wo2[32 + r31]};
  const float bo2v = bo2[0];
#pragma unroll
  for (int reg = 0; reg < 16; ++reg) {
    float h0 = tanh_fast(aO[0][reg] + bo1_[0]);
    float h1 = tanh_fast(aO[1][reg] + bo1_[1]);
    float p = h0 * wo2_[0] + h1 * wo2_[1];
#pragma unroll
    for (int mks = 16; mks >= 1; mks >>= 1) p += __shfl_xor(p, mks, 64);
    if (r31 == 0) {
      int row = (reg & 3) + 8 * (reg >> 2) + 4 * h;
      out[R0 + row] = p + bo2v;
    }
  }
#undef LDWP
}

extern "C" void kernel_launch(void* const* d_in, const int* in_sizes, int n_in,
                              void* d_out, int out_size, void* d_ws, size_t ws_size,
                              hipStream_t stream) {
  const float* prop  = (const float*)d_in[0];
  const float* annot = (const float*)d_in[1];
  const float* A     = (const float*)d_in[2];
  const float* Win   = (const float*)d_in[3];
  const float* bin   = (const float*)d_in[4];
  const float* Wr    = (const float*)d_in[5];
  const float* br    = (const float*)d_in[6];
  const float* Wz    = (const float*)d_in[7];
  const float* bz    = (const float*)d_in[8];
  const float* Wh    = (const float*)d_in[9];
  const float* bh    = (const float*)d_in[10];
  const float* Wo1   = (const float*)d_in[11];
  const float* bo1   = (const float*)d_in[12];
  const float* Wo2   = (const float*)d_in[13];
  const float* bo2   = (const float*)d_in[14];
  float* out = (float*)d_out;

  char* ws = (char*)d_ws;
  __bf16* Bt   = (__bf16*)ws;                              // [2][64][16384] bf16 = 4 MB
  float*  part = (float*)(ws + (size_t)4 * 1024 * 1024);   // [8][256][32][64] f32 = 16 MB
  __bf16* Wp   = (__bf16*)(ws + (size_t)20 * 1024 * 1024); // 60 KB

  k_pack<<<dim3(60), 64, 0, stream>>>(Wr, Wz, Wh, Wo1, Wp);
  k_build_bt<<<dim3(Nn / 64, Ee, Bz), 256, 0, stream>>>(prop, Win, bin, Bt);
  k_big_gemm<<<dim3(256), 512, 0, stream>>>(A, Bt, part);
  k_gru<<<dim3(NT), 64, 0, stream>>>(part, prop, annot, Wp,
                                     br, bz, bh, bo1, Wo2, bo2, out);
}

// Round 8
// 138.265 us; speedup vs baseline: 1.4207x; 1.2571x over previous
//
#include <hip/hip_runtime.h>
#include <hip/hip_bf16.h>
#include <stdint.h>

typedef __bf16 bf16x8 __attribute__((ext_vector_type(8)));
typedef float  f32x16 __attribute__((ext_vector_type(16)));
typedef float  f32x4  __attribute__((ext_vector_type(4)));

static constexpr int Bz = 2, Nn = 4096, Ee = 4, Dd = 64, ADim = 32;
static constexpr int Mm = Nn * Ee;        // 16384 reduction dim
static constexpr int KSEG = 4;            // K-segments
static constexpr int KLEN = Mm / KSEG;    // 4096 k per segment
static constexpr int NT = Bz * Nn / 32;   // 256 output row-tiles
static constexpr size_t SEGSTRIDE = (size_t)NT * 32 * 64;  // floats per kseg partial
static constexpr int PHK = 256;           // k per phase (1 KB/row granule)
static constexpr int NPH = KLEN / PHK;    // 16 phases

__device__ __forceinline__ bf16x8 cvt8(float4 a, float4 b) {
  bf16x8 r;
  r[0] = (__bf16)a.x; r[1] = (__bf16)a.y; r[2] = (__bf16)a.z; r[3] = (__bf16)a.w;
  r[4] = (__bf16)b.x; r[5] = (__bf16)b.y; r[6] = (__bf16)b.z; r[7] = (__bf16)b.w;
  return r;
}
__device__ __forceinline__ bf16x8 cvt8v(f32x4 a, f32x4 b) {
  bf16x8 r;
  r[0] = (__bf16)a[0]; r[1] = (__bf16)a[1]; r[2] = (__bf16)a[2]; r[3] = (__bf16)a[3];
  r[4] = (__bf16)b[0]; r[5] = (__bf16)b[1]; r[6] = (__bf16)b[2]; r[7] = (__bf16)b[3];
  return r;
}
__device__ __forceinline__ f32x16 zero16() {
  f32x16 z;
#pragma unroll
  for (int i = 0; i < 16; ++i) z[i] = 0.f;
  return z;
}
__device__ __forceinline__ f32x16 mm(bf16x8 a, bf16x8 b, f32x16 c) {
  return __builtin_amdgcn_mfma_f32_32x32x16_bf16(a, b, c, 0, 0, 0);
}
__device__ __forceinline__ float sigm(float x) { return 1.f / (1.f + __expf(-x)); }
__device__ __forceinline__ float tanh_fast(float x) {
  float e = __expf(2.f * x);
  return 1.f - 2.f / (e + 1.f);
}
__device__ __forceinline__ void async_lds16(const void* g, void* l) {
  __builtin_amdgcn_global_load_lds(
      (const __attribute__((address_space(1))) uint32_t*)g,
      (__attribute__((address_space(3))) uint32_t*)l, 16, 0, 0);
}

// -------- Kernel 0: pack GRU/head weights into bf16 MFMA B-fragments.
__global__ __launch_bounds__(64) void k_pack(
    const float* __restrict__ Wr, const float* __restrict__ Wz,
    const float* __restrict__ Wh, const float* __restrict__ Wo1,
    __bf16* __restrict__ Wp) {
  const int f = blockIdx.x, l = threadIdx.x;
  const int r31 = l & 31, h = l >> 5;
  const float* W; int L, fl;
  if (f < 16)      { W = Wr;  L = 128; fl = f; }
  else if (f < 32) { W = Wz;  L = 128; fl = f - 16; }
  else if (f < 48) { W = Wh;  L = 128; fl = f - 32; }
  else             { W = Wo1; L = 96;  fl = f - 48; }
  const int ks = fl >> 1, oh = fl & 1;
  const float* src = W + (size_t)(32 * oh + r31) * L + 16 * ks + 8 * h;
  float4 s0 = *reinterpret_cast<const float4*>(src);
  float4 s1 = *reinterpret_cast<const float4*>(src + 4);
  *reinterpret_cast<bf16x8*>(Wp + ((size_t)f * 64 + l) * 8) = cvt8(s0, s1);
}

// -------- Kernel 1: Bt[b][d][e*N+n] = sum_d' W_in[e][d][d'] * prop[b][n][d'] + b_in[e][d]
__global__ __launch_bounds__(256) void k_build_bt(
    const float* __restrict__ prop, const float* __restrict__ Win,
    const float* __restrict__ bin, __bf16* __restrict__ Bt) {
  const int nchunk = blockIdx.x;
  const int e = blockIdx.y, b = blockIdx.z;
  const int tid = threadIdx.x;
  const int w = tid >> 6, l = tid & 63;
  const int r31 = l & 31, h = l >> 5;
  const int oh = w & 1, ns = w >> 1;
  const int o_row = oh * 32 + r31;
  const int n_col = nchunk * 64 + ns * 32 + r31;
  const float* wbase = Win + ((size_t)e * 64 + o_row) * 64 + 8 * h;
  const float* pbase = prop + ((size_t)b * Nn + n_col) * 64 + 8 * h;
  f32x16 acc = zero16();
#pragma unroll
  for (int ks = 0; ks < 4; ++ks) {
    float4 w0 = *reinterpret_cast<const float4*>(wbase + 16 * ks);
    float4 w1 = *reinterpret_cast<const float4*>(wbase + 16 * ks + 4);
    float4 p0 = *reinterpret_cast<const float4*>(pbase + 16 * ks);
    float4 p1 = *reinterpret_cast<const float4*>(pbase + 16 * ks + 4);
    acc = mm(cvt8(w0, w1), cvt8(p0, p1), acc);
  }
#pragma unroll
  for (int reg = 0; reg < 16; ++reg) {
    int orow = oh * 32 + (reg & 3) + 8 * (reg >> 2) + 4 * h;
    float v = acc[reg] + bin[e * 64 + orow];
    Bt[((size_t)b * 64 + orow) * Mm + (size_t)e * Nn + n_col] = (__bf16)v;
  }
}

// -------- Kernel 2: split-K GEMM, v3.
// 256 blocks (1/CU), 8 waves. bid&7 <-> (kseg 0..3, batch) pins each (batch,
// kseg) Bt slice (512 KB) to one XCD -> L2-served re-stages.
// 4 tiles/block, 2 waves/tile split by OUTPUT COLUMNS (each wave: 32x32 acc,
// full k). A staged per phase as [4][32][256] f32 (128 KB): each
// global_load_lds issue = ONE row x 1 KB contiguous (DRAM-page-friendly).
// Bt window [64][256] bf16 (32 KB) staged alongside. Phase order rotated per
// block ((pp+g)&15) to decorrelate k-address bits 10-13 across blocks;
// accumulation order is commutative so result is unchanged.
// XOR swizzle unit^=(row&7) on global source AND LDS read (both-sides).
__global__ __launch_bounds__(512, 1) void k_big_gemm(
    const float* __restrict__ A, const __bf16* __restrict__ Bt,
    float* __restrict__ part) {
  __shared__ float  at[4][32][PHK];      // 128 KB
  __shared__ __bf16 btl[64][PHK];        // 32 KB   (total = 160 KiB exact)

  const int bid = blockIdx.x;            // 0..255
  const int kseg = bid & 3;
  const int bb   = (bid >> 2) & 1;       // batch; bid&7 -> XCD owns (kseg,bb)
  const int g    = bid >> 3;             // 0..31
  const int ph0  = g & 15;               // per-block phase rotation
  const int tid = threadIdx.x;
  const int w = tid >> 6, l = tid & 63;
  const int r31 = l & 31, h = l >> 5;
  const int t = w >> 1, q = w & 1;       // tile, column-half
  const int n0 = (g * 4 + t) * 32;
  const int tile = bb * 128 + g * 4 + t;
  const size_t kbase = (size_t)kseg * KLEN;

  const float*  Abase = A + ((size_t)(bb * Nn + n0)) * Mm + kbase;
  const __bf16* BtB   = Bt + (size_t)bb * 64 * Mm + kbase;

  // A stage: 16 issues/wave, issue j = one row (16q+j) x 1 KB contiguous.
#define ISSUE_A(p)                                                         \
  { _Pragma("unroll")                                                      \
    for (int j_ = 0; j_ < 16; ++j_) {                                      \
      const int row_ = 16 * q + j_;                                        \
      const float* src_ = Abase + (size_t)row_ * Mm + (size_t)(p) * PHK +  \
                          ((l ^ (row_ & 7)) * 4);                          \
      async_lds16(src_, (void*)&at[t][row_][0]);                           \
    } }
  // Bt stage: 4 issues/wave, issue i = rows {2i,2i+1} x 512 B each.
#define ISSUE_BT(p)                                                        \
  { _Pragma("unroll")                                                      \
    for (int i_ = 0; i_ < 4; ++i_) {                                       \
      const int rbase_ = 2 * (4 * w + i_);                                 \
      const int row_ = rbase_ + (l >> 5);                                  \
      const __bf16* src_ = BtB + (size_t)row_ * Mm + (size_t)(p) * PHK +   \
                           (((l & 31) ^ (row_ & 7)) * 8);                  \
      async_lds16(src_, (void*)&btl[rbase_][0]);                           \
    } }

  f32x16 acc = zero16();
  ISSUE_A(ph0);
  ISSUE_BT(ph0);

  const int swz = r31 & 7;
  const int brow = 32 * q + r31;

  for (int pp = 0; pp < NPH; ++pp) {
    asm volatile("s_waitcnt vmcnt(0)" ::: "memory");
    __syncthreads();                    // phase staged for all waves
#pragma unroll
    for (int s = 0; s < 16; ++s) {
      const int u0 = 4 * s + 2 * h;     // A 16B-unit (of 64)
      f32x4 fa0 = *reinterpret_cast<const f32x4*>(&at[t][r31][(u0 ^ swz) * 4]);
      f32x4 fa1 = *reinterpret_cast<const f32x4*>(&at[t][r31][((u0 + 1) ^ swz) * 4]);
      bf16x8 fb = *reinterpret_cast<const bf16x8*>(&btl[brow][((2 * s + h) ^ swz) * 8]);
      acc = mm(cvt8v(fa0, fa1), fb, acc);
    }
    __syncthreads();                    // all waves done reading this phase
    if (pp + 1 < NPH) {
      const int pn = (pp + 1 + ph0) & 15;
      ISSUE_A(pn);
      ISSUE_BT(pn);
    }
  }
#undef ISSUE_A
#undef ISSUE_BT

  // write 32x32 partial (this wave's column half) for its tile
  float* pb = part + (size_t)kseg * SEGSTRIDE + (size_t)tile * 32 * 64 + 32 * q;
#pragma unroll
  for (int reg = 0; reg < 16; ++reg) {
    int row = (reg & 3) + 8 * (reg >> 2) + 4 * h;
    pb[row * 64 + r31] = acc[reg];
  }
}

// -------- Kernel 3: fold split-K reduce (4 segs) + GRU gate update + head.
__global__ __launch_bounds__(64) void k_gru(
    const float* __restrict__ part, const float* __restrict__ prop,
    const float* __restrict__ annot, const __bf16* __restrict__ Wp,
    const float* __restrict__ br, const float* __restrict__ bz,
    const float* __restrict__ bh, const float* __restrict__ bo1,
    const float* __restrict__ Wo2, const float* __restrict__ bo2,
    float* __restrict__ out) {
  __shared__ float plds[32][68];
  __shared__ float tlds[32][68];
  const int tile = blockIdx.x;
  const int R0 = tile * 32;
  const int l = threadIdx.x;
  const int r31 = l & 31, h = l >> 5;

  bf16x8 xa[4], xp[4], xan[2];
  {
    const float* pt = part + ((size_t)tile * 32 + r31) * 64 + 8 * h;
    const float* pb = prop + (size_t)(R0 + r31) * 64 + 8 * h;
#pragma unroll
    for (int ks = 0; ks < 4; ++ks) {
      f32x4 s0, s1;
      s0[0] = s0[1] = s0[2] = s0[3] = 0.f;
      s1[0] = s1[1] = s1[2] = s1[3] = 0.f;
#pragma unroll
      for (int seg = 0; seg < KSEG; ++seg) {
        const float* pp = pt + seg * SEGSTRIDE + 16 * ks;
        f32x4 v0 = *reinterpret_cast<const f32x4*>(pp);
        f32x4 v1 = *reinterpret_cast<const f32x4*>(pp + 4);
        s0[0] += v0[0]; s0[1] += v0[1]; s0[2] += v0[2]; s0[3] += v0[3];
        s1[0] += v1[0]; s1[1] += v1[1]; s1[2] += v1[2]; s1[3] += v1[3];
      }
      xa[ks] = cvt8v(s0, s1);
      float4 p0 = *reinterpret_cast<const float4*>(pb + 16 * ks);
      float4 p1 = *reinterpret_cast<const float4*>(pb + 16 * ks + 4);
      xp[ks] = cvt8(p0, p1);
      *reinterpret_cast<float4*>(&plds[r31][16 * ks + 8 * h]) = p0;
      *reinterpret_cast<float4*>(&plds[r31][16 * ks + 8 * h + 4]) = p1;
    }
    const float* anb = annot + (size_t)(R0 + r31) * ADim + 8 * h;
#pragma unroll
    for (int ks = 0; ks < 2; ++ks) {
      float4 a0 = *reinterpret_cast<const float4*>(anb + 16 * ks);
      float4 a1 = *reinterpret_cast<const float4*>(anb + 16 * ks + 4);
      xan[ks] = cvt8(a0, a1);
    }
  }
  __syncthreads();

#define LDWP(base, ks, oh) \
  (*reinterpret_cast<const bf16x8*>(Wp + (((size_t)(base) + (ks) * 2 + (oh)) * 64 + l) * 8))

  f32x16 aR[2] = {zero16(), zero16()}, aZ[2] = {zero16(), zero16()};
#pragma unroll
  for (int ks = 0; ks < 8; ++ks) {
    bf16x8 af = (ks < 4) ? xa[ks] : xp[ks - 4];
#pragma unroll
    for (int oh = 0; oh < 2; ++oh) {
      aR[oh] = mm(af, LDWP(0, ks, oh), aR[oh]);
      aZ[oh] = mm(af, LDWP(16, ks, oh), aZ[oh]);
    }
  }
  const float br_[2] = {br[r31], br[32 + r31]};
  const float bz_[2] = {bz[r31], bz[32 + r31]};
  float propv[2][16], zv[2][16];
#pragma unroll
  for (int oh = 0; oh < 2; ++oh) {
#pragma unroll
    for (int reg = 0; reg < 16; ++reg) {
      int row = (reg & 3) + 8 * (reg >> 2) + 4 * h;
      int o = 32 * oh + r31;
      propv[oh][reg] = plds[row][o];
      float rv = sigm(aR[oh][reg] + br_[oh]);
      zv[oh][reg] = sigm(aZ[oh][reg] + bz_[oh]);
      tlds[row][o] = rv * propv[oh][reg];
    }
  }
  __syncthreads();
  bf16x8 xr[4];
#pragma unroll
  for (int ks = 0; ks < 4; ++ks) {
    float4 t0 = *reinterpret_cast<const float4*>(&tlds[r31][16 * ks + 8 * h]);
    float4 t1 = *reinterpret_cast<const float4*>(&tlds[r31][16 * ks + 8 * h + 4]);
    xr[ks] = cvt8(t0, t1);
  }
  f32x16 aH[2] = {zero16(), zero16()};
#pragma unroll
  for (int ks = 0; ks < 8; ++ks) {
    bf16x8 af = (ks < 4) ? xa[ks] : xr[ks - 4];
#pragma unroll
    for (int oh = 0; oh < 2; ++oh) aH[oh] = mm(af, LDWP(32, ks, oh), aH[oh]);
  }
  __syncthreads();
  const float bh_[2] = {bh[r31], bh[32 + r31]};
#pragma unroll
  for (int oh = 0; oh < 2; ++oh) {
#pragma unroll
    for (int reg = 0; reg < 16; ++reg) {
      int row = (reg & 3) + 8 * (reg >> 2) + 4 * h;
      int o = 32 * oh + r31;
      float hh = tanh_fast(aH[oh][reg] + bh_[oh]);
      float z = zv[oh][reg];
      tlds[row][o] = (1.f - z) * propv[oh][reg] + z * hh;
    }
  }
  __syncthreads();
  bf16x8 xn[4];
#pragma unroll
  for (int ks = 0; ks < 4; ++ks) {
    float4 t0 = *reinterpret_cast<const float4*>(&tlds[r31][16 * ks + 8 * h]);
    float4 t1 = *reinterpret_cast<const float4*>(&tlds[r31][16 * ks + 8 * h + 4]);
    xn[ks] = cvt8(t0, t1);
  }
  f32x16 aO[2] = {zero16(), zero16()};
#pragma unroll
  for (int ks = 0; ks < 6; ++ks) {
    bf16x8 af = (ks < 4) ? xn[ks] : xan[ks - 4];
#pragma unroll
    for (int oh = 0; oh < 2; ++oh) aO[oh] = mm(af, LDWP(48, ks, oh), aO[oh]);
  }
  const float bo1_[2] = {bo1[r31], bo1[32 + r31]};
  const float wo2_[2] = {Wo2[r31], Wo2[32 + r31]};
  const float bo2v = bo2[0];
#pragma unroll
  for (int reg = 0; reg < 16; ++reg) {
    float h0 = tanh_fast(aO[0][reg] + bo1_[0]);
    float h1 = tanh_fast(aO[1][reg] + bo1_[1]);
    float p = h0 * wo2_[0] + h1 * wo2_[1];
#pragma unroll
    for (int mks = 16; mks >= 1; mks >>= 1) p += __shfl_xor(p, mks, 64);
    if (r31 == 0) {
      int row = (reg & 3) + 8 * (reg >> 2) + 4 * h;
      out[R0 + row] = p + bo2v;
    }
  }
#undef LDWP
}

extern "C" void kernel_launch(void* const* d_in, const int* in_sizes, int n_in,
                              void* d_out, int out_size, void* d_ws, size_t ws_size,
                              hipStream_t stream) {
  const float* prop  = (const float*)d_in[0];
  const float* annot = (const float*)d_in[1];
  const float* A     = (const float*)d_in[2];
  const float* Win   = (const float*)d_in[3];
  const float* bin   = (const float*)d_in[4];
  const float* Wr    = (const float*)d_in[5];
  const float* br    = (const float*)d_in[6];
  const float* Wz    = (const float*)d_in[7];
  const float* bz    = (const float*)d_in[8];
  const float* Wh    = (const float*)d_in[9];
  const float* bh    = (const float*)d_in[10];
  const float* Wo1   = (const float*)d_in[11];
  const float* bo1   = (const float*)d_in[12];
  const float* Wo2   = (const float*)d_in[13];
  const float* bo2   = (const float*)d_in[14];
  float* out = (float*)d_out;

  char* ws = (char*)d_ws;
  __bf16* Bt   = (__bf16*)ws;                              // [2][64][16384] bf16 = 4 MB
  float*  part = (float*)(ws + (size_t)4 * 1024 * 1024);   // [4][256][32][64] f32 = 8 MB
  __bf16* Wp   = (__bf16*)(ws + (size_t)12 * 1024 * 1024); // 60 KB

  k_pack<<<dim3(60), 64, 0, stream>>>(Wr, Wz, Wh, Wo1, Wp);
  k_build_bt<<<dim3(Nn / 64, Ee, Bz), 256, 0, stream>>>(prop, Win, bin, Bt);
  k_big_gemm<<<dim3(256), 512, 0, stream>>>(A, Bt, part);
  k_gru<<<dim3(NT), 64, 0, stream>>>(part, prop, annot, Wp,
                                     br, bz, bh, bo1, Wo2, bo2, out);
}